// Round 5
// baseline (4239.807 us; speedup 1.0000x reference)
//
#include <hip/hip_runtime.h>

#define BB 32
#define TT 2048
#define DD 256
#define HH 512
#define NSL 8     // column slices per batch (one WG each)
#define SLW 64    // slice width (columns per WG)
#define CHW 68    // padded chunk width in h_lds (bank-conflict-free)

__device__ __forceinline__ float tanh_f(float x) {
    float e = __expf(2.f * x);
    return 1.f - 2.f / (e + 1.f);
}

// MALL exchange (known-good from R3): relaxed agent-scope 8B atomics.
// No fences: value+tag share one atomic word; publish depends (true data
// dependence) on all prior-step reads, so it cannot be visible early.
__device__ __forceinline__ unsigned long long mall_load(const unsigned long long* p) {
    return __hip_atomic_load(p, __ATOMIC_RELAXED, __HIP_MEMORY_SCOPE_AGENT);
}
__device__ __forceinline__ void mall_store(unsigned long long* p, unsigned long long v) {
    __hip_atomic_store(p, v, __ATOMIC_RELAXED, __HIP_MEMORY_SCOPE_AGENT);
}

// ---------------------------------------------------------------------------
// Kernel A: xw[t][b][n] = bh[n] + sum_d X[b][t][d] * Wxh[d][n]
// Written IN PLACE into the d_out Y region (same [T][B][H] layout).
// ---------------------------------------------------------------------------
__global__ __launch_bounds__(256) void xw_gemm(const float* __restrict__ X,
                                               const float* __restrict__ Wxh,
                                               const float* __restrict__ bh,
                                               float* __restrict__ out) {
    __shared__ float As[16][68];
    __shared__ float Bs[16][68];
    const int tid = threadIdx.x;
    const int r0 = blockIdx.x * 64;
    const int n0 = blockIdx.y * 64;
    const int ty = tid >> 4, tx = tid & 15;

    float acc[4][4];
#pragma unroll
    for (int i = 0; i < 4; i++)
#pragma unroll
        for (int j = 0; j < 4; j++) acc[i][j] = 0.f;

    const int arow = tid >> 2;
    const int akq  = (tid & 3) * 4;
    const int brow = tid >> 4;
    const int bq   = (tid & 15) * 4;

    for (int k0 = 0; k0 < DD; k0 += 16) {
        float4 a4 = *reinterpret_cast<const float4*>(
            &X[(size_t)(r0 + arow) * DD + k0 + akq]);
        As[akq + 0][arow] = a4.x;
        As[akq + 1][arow] = a4.y;
        As[akq + 2][arow] = a4.z;
        As[akq + 3][arow] = a4.w;
        float4 b4 = *reinterpret_cast<const float4*>(
            &Wxh[(size_t)(k0 + brow) * HH + n0 + bq]);
        *reinterpret_cast<float4*>(&Bs[brow][bq]) = b4;
        __syncthreads();
#pragma unroll
        for (int kk = 0; kk < 16; kk++) {
            float a0 = As[kk][ty * 4 + 0];
            float a1 = As[kk][ty * 4 + 1];
            float a2 = As[kk][ty * 4 + 2];
            float a3 = As[kk][ty * 4 + 3];
            float4 bv = *reinterpret_cast<const float4*>(&Bs[kk][tx * 4]);
            acc[0][0] += a0 * bv.x; acc[0][1] += a0 * bv.y; acc[0][2] += a0 * bv.z; acc[0][3] += a0 * bv.w;
            acc[1][0] += a1 * bv.x; acc[1][1] += a1 * bv.y; acc[1][2] += a1 * bv.z; acc[1][3] += a1 * bv.w;
            acc[2][0] += a2 * bv.x; acc[2][1] += a2 * bv.y; acc[2][2] += a2 * bv.z; acc[2][3] += a2 * bv.w;
            acc[3][0] += a3 * bv.x; acc[3][1] += a3 * bv.y; acc[3][2] += a3 * bv.z; acc[3][3] += a3 * bv.w;
        }
        __syncthreads();
    }
    float4 bias = *reinterpret_cast<const float4*>(&bh[n0 + tx * 4]);
#pragma unroll
    for (int i = 0; i < 4; i++) {
        int r = r0 + ty * 4 + i;
        int b = r >> 11;
        int t = r & (TT - 1);
        float4 o;
        o.x = acc[i][0] + bias.x;
        o.y = acc[i][1] + bias.y;
        o.z = acc[i][2] + bias.z;
        o.w = acc[i][3] + bias.w;
        *reinterpret_cast<float4*>(
            &out[((size_t)t * BB + b) * HH + n0 + tx * 4]) = o;
    }
}

// ---------------------------------------------------------------------------
// Kernel B: distributed scan, pure-MALL exchange, shuffle-reduce.
// 256 WGs = 32 batches x 8 column slices. Thread (o = tid>>3, ks = tid&7):
// weights w[j] = Whh[ks*64+j][n0+o] in 64 VGPRs. Per step:
//   matvec own k-chunk from h_lds[t&1][ks][..] (conflict-free broadcast)
//   -> 3-hop __shfl_xor reduce within the 8-lane group (no LDS, no barrier)
//   -> ks==0 lane: tanh(+xw), publish {val,tag=t+1} to MALL, store Y,
//      write own chunk of h_lds[(t+1)&1], prefetch next xw
//   -> threads with ks != s poll their one foreign slot, fill h_lds[(t+1)&1]
//   -> ONE __syncthreads.
// WAR safety: h_lds double-buffered by t&1; MALL slot reuse only at t+2 and
// the publish-follows-read transitive chain closes the gap-2 window (R3 arg).
// Tags 1..2048 never match the 0xAA poison => no workspace init needed.
// ---------------------------------------------------------------------------
__global__ __launch_bounds__(512) void scan_kernel(const float* __restrict__ Whh,
                                                   float* __restrict__ Y,
                                                   unsigned long long* __restrict__ ex) {
    __shared__ float h_lds[2][NSL][CHW];
    const int tid = threadIdx.x;
    const int bid = blockIdx.x;
    const int s = bid >> 5;       // slice 0..7
    const int b = bid & 31;       // batch 0..31
    const int n0 = s * SLW;
    const int o  = tid >> 3;      // output column within slice, 0..63
    const int ks = tid & 7;       // k-chunk, 0..7
    const int k0 = ks * 64;
    const bool fin = (ks == 0);   // finisher lane for output o
    const bool foreign = (ks != s);

    // one-time: weights for column n0+o, rows k0..k0+63
    float w[64];
#pragma unroll
    for (int j = 0; j < 64; j++)
        w[j] = Whh[(size_t)(k0 + j) * HH + n0 + o];

    // h_0 = 0
    for (int i = tid; i < NSL * CHW; i += 512)
        (&h_lds[0][0][0])[i] = 0.f;
    __syncthreads();

    // xw for t=0 (precomputed in place in Y)
    float xw_cur = fin ? Y[(size_t)b * HH + n0 + o] : 0.f;

    for (int t = 0; t < TT; t++) {
        const int p = t & 1;
        const float* hp = h_lds[p][ks];
        float a0 = 0.f, a1 = 0.f, a2 = 0.f, a3 = 0.f;
#pragma unroll
        for (int j = 0; j < 64; j += 4) {
            float4 h4 = *reinterpret_cast<const float4*>(&hp[j]);
            a0 += h4.x * w[j + 0];
            a1 += h4.y * w[j + 1];
            a2 += h4.z * w[j + 2];
            a3 += h4.w * w[j + 3];
        }
        float sum = (a0 + a1) + (a2 + a3);
        sum += __shfl_xor(sum, 1);
        sum += __shfl_xor(sum, 2);
        sum += __shfl_xor(sum, 4);

        if (fin) {
            float hn = tanh_f(sum + xw_cur);
            unsigned long long pk =
                ((unsigned long long)(unsigned)(t + 1) << 32) |
                (unsigned long long)__float_as_uint(hn);
            mall_store(&ex[(((size_t)p * BB + b) << 9) + n0 + o], pk);
            Y[((size_t)t * BB + b) * HH + n0 + o] = hn;
            h_lds[p ^ 1][s][o] = hn;    // own chunk for next step
            if (t + 1 < TT)
                xw_cur = Y[((size_t)(t + 1) * BB + b) * HH + n0 + o];
        }

        if (t + 1 < TT) {
            if (foreign) {
                unsigned long long* q =
                    &ex[(((size_t)p * BB + b) << 9) + k0 + o];
                const unsigned want = (unsigned)(t + 1);
                unsigned long long v;
                do {
                    v = mall_load(q);
                } while ((unsigned)(v >> 32) != want);
                h_lds[p ^ 1][ks][o] = __uint_as_float((unsigned)v);
            }
            __syncthreads();
        }
    }
}

// ---------------------------------------------------------------------------
// Attention, split for full-chip parallelism.
//   v[b] = KW @ (QW^T Y[T-1,b]);  sc[b,t] = tanh(Y[t,b,:].v[b]);
//   A = softmax_t(sc);  c[b,:] = sum_t A[b,t] Y[t,b,:]
// ---------------------------------------------------------------------------
__global__ __launch_bounds__(512) void attn_v(const float* __restrict__ QW,
                                              const float* __restrict__ KW,
                                              const float* __restrict__ Y,
                                              float* __restrict__ vbuf) {
    __shared__ float yl[HH];
    __shared__ float q0[DD];
    const int tid = threadIdx.x;
    const int b = blockIdx.x;

    yl[tid] = Y[((size_t)(TT - 1) * BB + b) * HH + tid];
    __syncthreads();

    if (tid < DD) {
        float s = 0.f;
#pragma unroll 8
        for (int h = 0; h < HH; h++) s += yl[h] * QW[(size_t)h * DD + tid];
        q0[tid] = s;
    }
    __syncthreads();

    float s = 0.f;
#pragma unroll 4
    for (int d = 0; d < DD; d += 4) {
        float4 kw = *reinterpret_cast<const float4*>(&KW[(size_t)tid * DD + d]);
        float4 q4 = *reinterpret_cast<const float4*>(&q0[d]);
        s += kw.x * q4.x + kw.y * q4.y + kw.z * q4.z + kw.w * q4.w;
    }
    vbuf[(size_t)b * HH + tid] = s;
}

// grid 256 = (b, chunk of 256 t's); 8 waves, each wave 32 t's
__global__ __launch_bounds__(512) void attn_sc(const float* __restrict__ Y,
                                               const float* __restrict__ vbuf,
                                               float* __restrict__ sc) {
    __shared__ float vv[HH];
    const int tid = threadIdx.x;
    const int b = blockIdx.x >> 3;
    const int t0 = (blockIdx.x & 7) * 256;
    const int w = tid >> 6;
    const int l = tid & 63;

    vv[tid] = vbuf[(size_t)b * HH + tid];
    __syncthreads();

    float4 v0 = *reinterpret_cast<const float4*>(&vv[l * 8]);
    float4 v1 = *reinterpret_cast<const float4*>(&vv[l * 8 + 4]);
    for (int i = 0; i < 32; i++) {
        int t = t0 + i * 8 + w;
        const float* yr = &Y[((size_t)t * BB + b) * HH + l * 8];
        float4 y0 = *reinterpret_cast<const float4*>(yr);
        float4 y1 = *reinterpret_cast<const float4*>(yr + 4);
        float s = y0.x * v0.x + y0.y * v0.y + y0.z * v0.z + y0.w * v0.w +
                  y1.x * v1.x + y1.y * v1.y + y1.z * v1.z + y1.w * v1.w;
#pragma unroll
        for (int off = 32; off > 0; off >>= 1) s += __shfl_xor(s, off);
        if (l == 0) sc[(size_t)b * TT + t] = tanh_f(s);
    }
}

// grid 32: softmax over sc[b][0..T) in place
__global__ __launch_bounds__(512) void attn_sm(float* __restrict__ sc) {
    __shared__ float sl[TT];
    __shared__ float red[16];
    const int tid = threadIdx.x;
    const int b = blockIdx.x;
    const int w = tid >> 6;
    const int l = tid & 63;

    for (int i = tid; i < TT; i += 512) sl[i] = sc[(size_t)b * TT + i];
    __syncthreads();

    float m = -1e30f;
    for (int i = tid; i < TT; i += 512) m = fmaxf(m, sl[i]);
#pragma unroll
    for (int off = 32; off > 0; off >>= 1) m = fmaxf(m, __shfl_xor(m, off));
    if (l == 0) red[w] = m;
    __syncthreads();
    float gm = red[0];
#pragma unroll
    for (int i = 1; i < 8; i++) gm = fmaxf(gm, red[i]);

    float ls = 0.f;
    for (int i = tid; i < TT; i += 512) {
        float e = __expf(sl[i] - gm);
        sl[i] = e;
        ls += e;
    }
#pragma unroll
    for (int off = 32; off > 0; off >>= 1) ls += __shfl_xor(ls, off);
    __syncthreads();
    if (l == 0) red[8 + w] = ls;
    __syncthreads();
    float tot = 0.f;
#pragma unroll
    for (int i = 0; i < 8; i++) tot += red[8 + i];
    float inv = 1.f / tot;
    for (int i = tid; i < TT; i += 512) sc[(size_t)b * TT + i] = sl[i] * inv;
}

// grid 256 = (b, chunk): partial context over 256 t's
__global__ __launch_bounds__(512) void attn_ctx(const float* __restrict__ Y,
                                                const float* __restrict__ sc,
                                                float* __restrict__ cpart) {
    __shared__ float al[256];
    const int tid = threadIdx.x;
    const int b = blockIdx.x >> 3;
    const int ch = blockIdx.x & 7;
    const int t0 = ch * 256;

    if (tid < 256) al[tid] = sc[(size_t)b * TT + t0 + tid];
    __syncthreads();

    float acc = 0.f;
    for (int i = 0; i < 256; i += 4) {
        float4 a4 = *reinterpret_cast<const float4*>(&al[i]);
        acc += a4.x * Y[((size_t)(t0 + i + 0) * BB + b) * HH + tid];
        acc += a4.y * Y[((size_t)(t0 + i + 1) * BB + b) * HH + tid];
        acc += a4.z * Y[((size_t)(t0 + i + 2) * BB + b) * HH + tid];
        acc += a4.w * Y[((size_t)(t0 + i + 3) * BB + b) * HH + tid];
    }
    cpart[((size_t)blockIdx.x) * HH + tid] = acc;
}

// grid 32: sum the 8 chunk partials
__global__ __launch_bounds__(512) void attn_fin(const float* __restrict__ cpart,
                                                float* __restrict__ c) {
    const int tid = threadIdx.x;
    const int b = blockIdx.x;
    float acc = 0.f;
#pragma unroll
    for (int ch = 0; ch < 8; ch++)
        acc += cpart[((size_t)(b * 8 + ch)) * HH + tid];
    c[(size_t)b * HH + tid] = acc;
}

// ---------------------------------------------------------------------------
extern "C" void kernel_launch(void* const* d_in, const int* in_sizes, int n_in,
                              void* d_out, int out_size, void* d_ws, size_t ws_size,
                              hipStream_t stream) {
    const float* X   = (const float*)d_in[0];
    const float* Wxh = (const float*)d_in[1];
    const float* Whh = (const float*)d_in[2];
    const float* bh  = (const float*)d_in[3];
    const float* QW  = (const float*)d_in[4];
    const float* KW  = (const float*)d_in[5];
    float* out  = (float*)d_out;
    float* Ybuf = out;                                   // [T][B][H]
    float* cbuf = out + (size_t)TT * BB * HH;            // [B][H]

    char* ws = (char*)d_ws;
    unsigned long long* ex = (unsigned long long*)ws;         // 256 KiB
    float* vbuf  = (float*)(ws + (2 * BB * HH) * 8);          // 64 KiB
    float* scbuf = (float*)(ws + 262144 + 65536);             // 256 KiB
    float* cpart = (float*)(ws + 262144 + 65536 + 262144);    // 512 KiB

    dim3 ga(BB * TT / 64, HH / 64);
    xw_gemm<<<ga, 256, 0, stream>>>(X, Wxh, bh, Ybuf);
    scan_kernel<<<BB * NSL, 512, 0, stream>>>(Whh, Ybuf, ex);
    attn_v<<<BB, 512, 0, stream>>>(QW, KW, Ybuf, vbuf);
    attn_sc<<<BB * 8, 512, 0, stream>>>(Ybuf, vbuf, scbuf);
    attn_sm<<<BB, 512, 0, stream>>>(scbuf);
    attn_ctx<<<BB * 8, 512, 0, stream>>>(Ybuf, scbuf, cpart);
    attn_fin<<<BB, 512, 0, stream>>>(cpart, cbuf);
}

// Round 6
// 2963.940 us; speedup vs baseline: 1.4305x; 1.4305x over previous
//
#include <hip/hip_runtime.h>

#define BB 32
#define TT 2048
#define DD 256
#define HH 512
#define NSL 8     // column slices per batch (one WG each)
#define SLW 64    // slice width (columns per WG)
#define CHW 68    // padded row width in h_lds (disjoint bank groups per ks)

__device__ __forceinline__ float tanh_f(float x) {
    float e = __expf(2.f * x);
    return 1.f - 2.f / (e + 1.f);
}

// MALL exchange (known-good from R3): relaxed agent-scope 8B atomics.
// No fences: value+tag share one atomic word; publish depends (true data
// dependence) on all prior-step reads, so it cannot be visible early.
__device__ __forceinline__ unsigned long long mall_load(const unsigned long long* p) {
    return __hip_atomic_load(p, __ATOMIC_RELAXED, __HIP_MEMORY_SCOPE_AGENT);
}
__device__ __forceinline__ void mall_store(unsigned long long* p, unsigned long long v) {
    __hip_atomic_store(p, v, __ATOMIC_RELAXED, __HIP_MEMORY_SCOPE_AGENT);
}

// ---------------------------------------------------------------------------
// Kernel A: xw[t][b][n] = bh[n] + sum_d X[b][t][d] * Wxh[d][n]
// Written IN PLACE into the d_out Y region (same [T][B][H] layout).
// ---------------------------------------------------------------------------
__global__ __launch_bounds__(256) void xw_gemm(const float* __restrict__ X,
                                               const float* __restrict__ Wxh,
                                               const float* __restrict__ bh,
                                               float* __restrict__ out) {
    __shared__ float As[16][68];
    __shared__ float Bs[16][68];
    const int tid = threadIdx.x;
    const int r0 = blockIdx.x * 64;
    const int n0 = blockIdx.y * 64;
    const int ty = tid >> 4, tx = tid & 15;

    float acc[4][4];
#pragma unroll
    for (int i = 0; i < 4; i++)
#pragma unroll
        for (int j = 0; j < 4; j++) acc[i][j] = 0.f;

    const int arow = tid >> 2;
    const int akq  = (tid & 3) * 4;
    const int brow = tid >> 4;
    const int bq   = (tid & 15) * 4;

    for (int k0 = 0; k0 < DD; k0 += 16) {
        float4 a4 = *reinterpret_cast<const float4*>(
            &X[(size_t)(r0 + arow) * DD + k0 + akq]);
        As[akq + 0][arow] = a4.x;
        As[akq + 1][arow] = a4.y;
        As[akq + 2][arow] = a4.z;
        As[akq + 3][arow] = a4.w;
        float4 b4 = *reinterpret_cast<const float4*>(
            &Wxh[(size_t)(k0 + brow) * HH + n0 + bq]);
        *reinterpret_cast<float4*>(&Bs[brow][bq]) = b4;
        __syncthreads();
#pragma unroll
        for (int kk = 0; kk < 16; kk++) {
            float a0 = As[kk][ty * 4 + 0];
            float a1 = As[kk][ty * 4 + 1];
            float a2 = As[kk][ty * 4 + 2];
            float a3 = As[kk][ty * 4 + 3];
            float4 bv = *reinterpret_cast<const float4*>(&Bs[kk][tx * 4]);
            acc[0][0] += a0 * bv.x; acc[0][1] += a0 * bv.y; acc[0][2] += a0 * bv.z; acc[0][3] += a0 * bv.w;
            acc[1][0] += a1 * bv.x; acc[1][1] += a1 * bv.y; acc[1][2] += a1 * bv.z; acc[1][3] += a1 * bv.w;
            acc[2][0] += a2 * bv.x; acc[2][1] += a2 * bv.y; acc[2][2] += a2 * bv.z; acc[2][3] += a2 * bv.w;
            acc[3][0] += a3 * bv.x; acc[3][1] += a3 * bv.y; acc[3][2] += a3 * bv.z; acc[3][3] += a3 * bv.w;
        }
        __syncthreads();
    }
    float4 bias = *reinterpret_cast<const float4*>(&bh[n0 + tx * 4]);
#pragma unroll
    for (int i = 0; i < 4; i++) {
        int r = r0 + ty * 4 + i;
        int b = r >> 11;
        int t = r & (TT - 1);
        float4 o;
        o.x = acc[i][0] + bias.x;
        o.y = acc[i][1] + bias.y;
        o.z = acc[i][2] + bias.z;
        o.w = acc[i][3] + bias.w;
        *reinterpret_cast<float4*>(
            &out[((size_t)t * BB + b) * HH + n0 + tx * 4]) = o;
    }
}

// ---------------------------------------------------------------------------
// Kernel B: distributed scan. Pure-MALL exchange (R3 semantics) +
// wave-coalesced polls + in-wave shuffle reduce + ONE barrier per step.
//
// 256 WGs = 32 batches x 8 slices. Thread (w = tid>>6, l = tid&63):
//   column c = w*8 + (l>>3) within slice, k-chunk ks = l&7.
//   Weights w[j] = Whh[ks*64+j][n0+c] in 64 VGPRs (one-time load).
// Per step t (p = t&1):
//   matvec: 16x ds_read_b128 from h_lds[p][ks][..] (padded: conflict-free
//     8-way broadcast) x 64 FMAs -> shuffle-xor(1,2,4) reduce over ks
//   finisher (l&7==0): tanh(+xw) -> publish {val,tag=t+1} to MALL slot
//     n0+c (8 consecutive slots per wave), write h_lds[p^1][s][c] (own
//     slice locally, no self-poll), store Y, prefetch next xw
//   poll: thread tid polls slot tid == element tid (wave w polls row w,
//     64 consecutive slots = 8 cachelines -> coalesced); waves with
//     w==s skip (filled locally). Fill h_lds[p^1][w][l].
//   ONE __syncthreads.
// WAR: h_lds double-buffered by t&1; step-t fill writes p^1 while matvec
// reads p, and the end-of-step barrier separates reuse. MALL slot reuse at
// t+2 is safe by the publish-follows-read transitive chain (every WG reads
// every slot each step). Tags 1..2048 never match 0xAA poison => no init.
// ---------------------------------------------------------------------------
__global__ __launch_bounds__(512) void scan_kernel(const float* __restrict__ Whh,
                                                   float* __restrict__ Y,
                                                   unsigned long long* __restrict__ ex) {
    __shared__ float h_lds[2][NSL][CHW];
    const int tid = threadIdx.x;
    const int bid = blockIdx.x;
    const int s = bid >> 5;        // slice 0..7
    const int b = bid & 31;        // batch 0..31
    const int n0 = s * SLW;
    const int w = tid >> 6;        // wave id == polled row
    const int l = tid & 63;
    const int c  = w * 8 + (l >> 3);   // column within slice
    const int ks = l & 7;              // k-chunk
    const bool fin = (ks == 0);
    const bool dopoll = (w != s);      // own row filled locally by finishers

    // one-time: weights for column n0+c, k-rows ks*64..ks*64+63
    float wv[64];
#pragma unroll
    for (int j = 0; j < 64; j++)
        wv[j] = Whh[(size_t)(ks * 64 + j) * HH + n0 + c];

    // h_0 = 0 (both buffers, cheap)
    for (int i = tid; i < 2 * NSL * CHW; i += 512)
        (&h_lds[0][0][0])[i] = 0.f;
    __syncthreads();

    // xw for t=0 (precomputed in place in Y)
    float xw_cur = fin ? Y[(size_t)b * HH + n0 + c] : 0.f;

    for (int t = 0; t < TT; t++) {
        const int p = t & 1;
        const float* hp = h_lds[p][ks];
        float a0 = 0.f, a1 = 0.f, a2 = 0.f, a3 = 0.f;
#pragma unroll
        for (int j = 0; j < 64; j += 4) {
            float4 h4 = *reinterpret_cast<const float4*>(&hp[j]);
            a0 += h4.x * wv[j + 0];
            a1 += h4.y * wv[j + 1];
            a2 += h4.z * wv[j + 2];
            a3 += h4.w * wv[j + 3];
        }
        float sum = (a0 + a1) + (a2 + a3);
        sum += __shfl_xor(sum, 1);
        sum += __shfl_xor(sum, 2);
        sum += __shfl_xor(sum, 4);

        if (fin) {
            float hn = tanh_f(sum + xw_cur);
            if (t + 1 < TT) {
                unsigned long long pk =
                    ((unsigned long long)(unsigned)(t + 1) << 32) |
                    (unsigned long long)__float_as_uint(hn);
                mall_store(&ex[(((size_t)p * BB + b) << 9) + n0 + c], pk);
                h_lds[p ^ 1][s][c] = hn;     // own slice, local
            }
            Y[((size_t)t * BB + b) * HH + n0 + c] = hn;
            if (t + 1 < TT)
                xw_cur = Y[((size_t)(t + 1) * BB + b) * HH + n0 + c];
        }

        if (t + 1 < TT) {
            if (dopoll) {
                unsigned long long* q = &ex[(((size_t)p * BB + b) << 9) + tid];
                const unsigned want = (unsigned)(t + 1);
                unsigned long long v;
                do {
                    v = mall_load(q);
                } while ((unsigned)(v >> 32) != want);
                h_lds[p ^ 1][w][l] = __uint_as_float((unsigned)v);
            }
            __syncthreads();   // the only barrier per step
        }
    }
}

// ---------------------------------------------------------------------------
// Attention, split for full-chip parallelism.
//   v[b] = KW @ (QW^T Y[T-1,b]);  sc[b,t] = tanh(Y[t,b,:].v[b]);
//   A = softmax_t(sc);  c[b,:] = sum_t A[b,t] Y[t,b,:]
// ---------------------------------------------------------------------------
__global__ __launch_bounds__(512) void attn_v(const float* __restrict__ QW,
                                              const float* __restrict__ KW,
                                              const float* __restrict__ Y,
                                              float* __restrict__ vbuf) {
    __shared__ float yl[HH];
    __shared__ float q0[DD];
    const int tid = threadIdx.x;
    const int b = blockIdx.x;

    yl[tid] = Y[((size_t)(TT - 1) * BB + b) * HH + tid];
    __syncthreads();

    if (tid < DD) {
        float s = 0.f;
#pragma unroll 8
        for (int h = 0; h < HH; h++) s += yl[h] * QW[(size_t)h * DD + tid];
        q0[tid] = s;
    }
    __syncthreads();

    float s = 0.f;
#pragma unroll 4
    for (int d = 0; d < DD; d += 4) {
        float4 kw = *reinterpret_cast<const float4*>(&KW[(size_t)tid * DD + d]);
        float4 q4 = *reinterpret_cast<const float4*>(&q0[d]);
        s += kw.x * q4.x + kw.y * q4.y + kw.z * q4.z + kw.w * q4.w;
    }
    vbuf[(size_t)b * HH + tid] = s;
}

// grid 256 = (b, chunk of 256 t's); 8 waves, each wave 32 t's
__global__ __launch_bounds__(512) void attn_sc(const float* __restrict__ Y,
                                               const float* __restrict__ vbuf,
                                               float* __restrict__ sc) {
    __shared__ float vv[HH];
    const int tid = threadIdx.x;
    const int b = blockIdx.x >> 3;
    const int t0 = (blockIdx.x & 7) * 256;
    const int w = tid >> 6;
    const int l = tid & 63;

    vv[tid] = vbuf[(size_t)b * HH + tid];
    __syncthreads();

    float4 v0 = *reinterpret_cast<const float4*>(&vv[l * 8]);
    float4 v1 = *reinterpret_cast<const float4*>(&vv[l * 8 + 4]);
    for (int i = 0; i < 32; i++) {
        int t = t0 + i * 8 + w;
        const float* yr = &Y[((size_t)t * BB + b) * HH + l * 8];
        float4 y0 = *reinterpret_cast<const float4*>(yr);
        float4 y1 = *reinterpret_cast<const float4*>(yr + 4);
        float s = y0.x * v0.x + y0.y * v0.y + y0.z * v0.z + y0.w * v0.w +
                  y1.x * v1.x + y1.y * v1.y + y1.z * v1.z + y1.w * v1.w;
#pragma unroll
        for (int off = 32; off > 0; off >>= 1) s += __shfl_xor(s, off);
        if (l == 0) sc[(size_t)b * TT + t] = tanh_f(s);
    }
}

// grid 32: softmax over sc[b][0..T) in place
__global__ __launch_bounds__(512) void attn_sm(float* __restrict__ sc) {
    __shared__ float sl[TT];
    __shared__ float red[16];
    const int tid = threadIdx.x;
    const int b = blockIdx.x;
    const int w = tid >> 6;
    const int l = tid & 63;

    for (int i = tid; i < TT; i += 512) sl[i] = sc[(size_t)b * TT + i];
    __syncthreads();

    float m = -1e30f;
    for (int i = tid; i < TT; i += 512) m = fmaxf(m, sl[i]);
#pragma unroll
    for (int off = 32; off > 0; off >>= 1) m = fmaxf(m, __shfl_xor(m, off));
    if (l == 0) red[w] = m;
    __syncthreads();
    float gm = red[0];
#pragma unroll
    for (int i = 1; i < 8; i++) gm = fmaxf(gm, red[i]);

    float ls = 0.f;
    for (int i = tid; i < TT; i += 512) {
        float e = __expf(sl[i] - gm);
        sl[i] = e;
        ls += e;
    }
#pragma unroll
    for (int off = 32; off > 0; off >>= 1) ls += __shfl_xor(ls, off);
    __syncthreads();
    if (l == 0) red[8 + w] = ls;
    __syncthreads();
    float tot = 0.f;
#pragma unroll
    for (int i = 0; i < 8; i++) tot += red[8 + i];
    float inv = 1.f / tot;
    for (int i = tid; i < TT; i += 512) sc[(size_t)b * TT + i] = sl[i] * inv;
}

// grid 256 = (b, chunk): partial context over 256 t's
__global__ __launch_bounds__(512) void attn_ctx(const float* __restrict__ Y,
                                                const float* __restrict__ sc,
                                                float* __restrict__ cpart) {
    __shared__ float al[256];
    const int tid = threadIdx.x;
    const int b = blockIdx.x >> 3;
    const int ch = blockIdx.x & 7;
    const int t0 = ch * 256;

    if (tid < 256) al[tid] = sc[(size_t)b * TT + t0 + tid];
    __syncthreads();

    float acc = 0.f;
    for (int i = 0; i < 256; i += 4) {
        float4 a4 = *reinterpret_cast<const float4*>(&al[i]);
        acc += a4.x * Y[((size_t)(t0 + i + 0) * BB + b) * HH + tid];
        acc += a4.y * Y[((size_t)(t0 + i + 1) * BB + b) * HH + tid];
        acc += a4.z * Y[((size_t)(t0 + i + 2) * BB + b) * HH + tid];
        acc += a4.w * Y[((size_t)(t0 + i + 3) * BB + b) * HH + tid];
    }
    cpart[((size_t)blockIdx.x) * HH + tid] = acc;
}

// grid 32: sum the 8 chunk partials
__global__ __launch_bounds__(512) void attn_fin(const float* __restrict__ cpart,
                                                float* __restrict__ c) {
    const int tid = threadIdx.x;
    const int b = blockIdx.x;
    float acc = 0.f;
#pragma unroll
    for (int ch = 0; ch < 8; ch++)
        acc += cpart[((size_t)(b * 8 + ch)) * HH + tid];
    c[(size_t)b * HH + tid] = acc;
}

// ---------------------------------------------------------------------------
extern "C" void kernel_launch(void* const* d_in, const int* in_sizes, int n_in,
                              void* d_out, int out_size, void* d_ws, size_t ws_size,
                              hipStream_t stream) {
    const float* X   = (const float*)d_in[0];
    const float* Wxh = (const float*)d_in[1];
    const float* Whh = (const float*)d_in[2];
    const float* bh  = (const float*)d_in[3];
    const float* QW  = (const float*)d_in[4];
    const float* KW  = (const float*)d_in[5];
    float* out  = (float*)d_out;
    float* Ybuf = out;                                   // [T][B][H]
    float* cbuf = out + (size_t)TT * BB * HH;            // [B][H]

    char* ws = (char*)d_ws;
    unsigned long long* ex = (unsigned long long*)ws;         // 256 KiB
    float* vbuf  = (float*)(ws + (2 * BB * HH) * 8);          // 64 KiB
    float* scbuf = (float*)(ws + 262144 + 65536);             // 256 KiB
    float* cpart = (float*)(ws + 262144 + 65536 + 262144);    // 512 KiB

    dim3 ga(BB * TT / 64, HH / 64);
    xw_gemm<<<ga, 256, 0, stream>>>(X, Wxh, bh, Ybuf);
    scan_kernel<<<BB * NSL, 512, 0, stream>>>(Whh, Ybuf, ex);
    attn_v<<<BB, 512, 0, stream>>>(QW, KW, Ybuf, vbuf);
    attn_sc<<<BB * 8, 512, 0, stream>>>(Ybuf, vbuf, scbuf);
    attn_sm<<<BB, 512, 0, stream>>>(scbuf);
    attn_ctx<<<BB * 8, 512, 0, stream>>>(Ybuf, scbuf, cpart);
    attn_fin<<<BB, 512, 0, stream>>>(cpart, cbuf);
}